// Round 13
// baseline (92.277 us; speedup 1.0000x reference)
//
#include <hip/hip_runtime.h>
#include <float.h>
#include <stdint.h>

// CorrLoss via bf16 MFMA, symmetric 128x128 tiles, BARRIER-FREE K-loop:
//   k0: cast fp32->bf16 and PACK into MFMA-fragment order:
//       fbp[R=row/32][Kb=k/16][lane][8] with lane l -> row R*32+(l&31),
//       k = Kb*16 + (l>>5)*8 .. +7. A wave's 32x32x16 fragment load is then
//       base + lane*16B: one coalesced 1KB global_load_dwordx4.
//   k1: 528 upper-tri tiles, 4 waves x (64x64 quadrant, 2x2 frags of
//       32x32x16). NO LDS staging, NO K-loop barriers: 4 coalesced loads +
//       4 MFMA per K=16, depth-1 register prefetch, compiler-scheduled
//       vmcnt pipelining. Exactly-once partial writes (no value atomics).
//   k2: 16-block fold -> done-counter last block -> out[0].

#define N_ROWS 4096
#define D_K    512
#define BT     128
#define NKB    (D_K / 16)              // 32 k-blocks of K=16
#define NTB    (N_ROWS / BT)           // 32
#define NTILES (NTB * (NTB + 1) / 2)   // 528
#define MARGIN 40.0f
#define FOLD_BLOCKS 16
#define RBLK   (32 * 64 * 8)           // elems per packed R-block (16384)

typedef __bf16 bf16_t;
typedef bf16_t bf16x8 __attribute__((ext_vector_type(8)));
typedef bf16_t bf16x4 __attribute__((ext_vector_type(4)));
typedef float  floatx16 __attribute__((ext_vector_type(16)));
typedef unsigned short ushort_t;

__device__ __forceinline__ ushort_t f2bf_rne(float x) {
    uint32_t u = __builtin_bit_cast(uint32_t, x);
    return (ushort_t)((u + 0x7FFFu + ((u >> 16) & 1u)) >> 16);
}

// ---- cast & pack: one block per 32-row R-block ----
__global__ __launch_bounds__(256) void cast_kernel(
    const float* __restrict__ f, ushort_t* __restrict__ fbp,
    int* __restrict__ counter)
{
    // lds[row][chunk]: 32 rows x 64 16B-chunks (8 bf16 each), chunk-XOR
    // swizzled (phys = logical ^ (row&7)) to break the stride-1024 aliasing.
    __shared__ __align__(16) ushort_t lds[32 * 512];
    const int R   = blockIdx.x;
    const int tid = threadIdx.x;
    if (R == 0 && tid == 0) *counter = 0;

    // phase 1: read 32x512 f32 coalesced, cvt, store swizzled 8B pieces
#pragma unroll
    for (int p = 0; p < 16; ++p) {
        const int fi   = p * 256 + tid;        // float4 index, 128 per row
        const int row  = fi >> 7;
        const int col4 = fi & 127;             // 4-elem groups
        const float4 v = *(const float4*)(f + ((size_t)(R * 32 + row) << 9) + col4 * 4);
        bf16x4 o;
        o[0] = __builtin_bit_cast(bf16_t, f2bf_rne(v.x));
        o[1] = __builtin_bit_cast(bf16_t, f2bf_rne(v.y));
        o[2] = __builtin_bit_cast(bf16_t, f2bf_rne(v.z));
        o[3] = __builtin_bit_cast(bf16_t, f2bf_rne(v.w));
        const int chunk = (col4 >> 1) ^ (row & 7);
        *(bf16x4*)(lds + row * 512 + chunk * 8 + (col4 & 1) * 4) = o;
    }
    __syncthreads();

    // phase 2: emit packed chunks, coalesced 16B writes
#pragma unroll
    for (int p = 0; p < 8; ++p) {
        const int c  = p * 256 + tid;          // 0..2047: Kb = c>>6, l = c&63
        const int l  = c & 63;
        const int r  = l & 31;
        const int lc = ((c >> 6) * 2 + (l >> 5)) ^ (r & 7);   // logical^swz
        const bf16x8 val = *(const bf16x8*)(lds + r * 512 + lc * 8);
        *(bf16x8*)(fbp + (size_t)R * RBLK + (size_t)c * 8) = val;
    }
}

#define MFMA4()                                                               \
    do {                                                                      \
        acc[0][0] = __builtin_amdgcn_mfma_f32_32x32x16_bf16(a0, b0, acc[0][0], 0, 0, 0); \
        acc[0][1] = __builtin_amdgcn_mfma_f32_32x32x16_bf16(a0, b1, acc[0][1], 0, 0, 0); \
        acc[1][0] = __builtin_amdgcn_mfma_f32_32x32x16_bf16(a1, b0, acc[1][0], 0, 0, 0); \
        acc[1][1] = __builtin_amdgcn_mfma_f32_32x32x16_bf16(a1, b1, acc[1][1], 0, 0, 0); \
    } while (0)

__global__ __launch_bounds__(256, 4) void gram_mfma_kernel(
    const ushort_t* __restrict__ fbp, const int* __restrict__ tgt,
    float* __restrict__ ap_part, float* __restrict__ an_part)
{
    __shared__ int tgI[BT];
    __shared__ int tgJ[BT];
    __shared__ float apRed[2 * BT], anRed[2 * BT];
    __shared__ float apRedT[2 * BT], anRedT[2 * BT];

    // flat block id -> upper-tri (bi, bj), row-major
    int bi = 0, rem = blockIdx.x;
    while (rem >= NTB - bi) { rem -= NTB - bi; ++bi; }
    const int bj = bi + rem;

    const int tid  = threadIdx.x;
    const int i0   = bi * BT;
    const int j0   = bj * BT;
    const int lane = tid & 63;
    const int wave = tid >> 6;
    const int wr   = wave >> 1;      // row half (0/1): 64 rows
    const int wc   = wave & 1;       // col half (0/1): 64 cols
    const int cl   = lane & 31;
    const int hh   = lane >> 5;

    if (tid < BT) tgI[tid] = tgt[i0 + tid];
    else          tgJ[tid - BT] = tgt[j0 + tid - BT];
    __syncthreads();

    const ushort_t* pA = fbp + (size_t)(bi * 4 + wr * 2) * RBLK + lane * 8;
    const ushort_t* pB = fbp + (size_t)(bj * 4 + wc * 2) * RBLK + lane * 8;

    floatx16 acc[2][2];
#pragma unroll
    for (int a = 0; a < 2; ++a)
#pragma unroll
        for (int b = 0; b < 2; ++b) acc[a][b] = (floatx16)0.0f;

    bf16x8 a0 = *(const bf16x8*)(pA);
    bf16x8 a1 = *(const bf16x8*)(pA + RBLK);
    bf16x8 b0 = *(const bf16x8*)(pB);
    bf16x8 b1 = *(const bf16x8*)(pB + RBLK);

#pragma unroll 4
    for (int kb = 0; kb < NKB - 1; ++kb) {
        const int o = (kb + 1) * 512;          // 64 chunks * 8 elems per Kb
        const bf16x8 na0 = *(const bf16x8*)(pA + o);
        const bf16x8 na1 = *(const bf16x8*)(pA + RBLK + o);
        const bf16x8 nb0 = *(const bf16x8*)(pB + o);
        const bf16x8 nb1 = *(const bf16x8*)(pB + RBLK + o);
        MFMA4();
        a0 = na0; a1 = na1; b0 = nb0; b1 = nb1;
    }
    MFMA4();

    // ---- epilogue (verified R12): C/D: col = lane&31,
    //      row = (reg&3) + 8*(reg>>2) + 4*(lane>>5) ----
    const int tj0 = tgJ[wc * 64 + cl];
    const int tj1 = tgJ[wc * 64 + 32 + cl];

    float apT[2], anT[2];
#pragma unroll
    for (int cg = 0; cg < 2; ++cg) { apT[cg] = FLT_MAX; anT[cg] = -FLT_MAX; }

#pragma unroll
    for (int rg = 0; rg < 2; ++rg) {
        const int rbase = wr * 64 + rg * 32 + 4 * hh;
#pragma unroll
        for (int reg = 0; reg < 16; ++reg) {
            const int row = rbase + (reg & 3) + 8 * (reg >> 2);
            const int ti = tgI[row];
            const float v0 = acc[rg][0][reg];
            const float v1 = acc[rg][1][reg];
            float vap = FLT_MAX, van = -FLT_MAX;
            if (ti == tj0) { vap = fminf(vap, v0); apT[0] = fminf(apT[0], v0); }
            else           { van = fmaxf(van, v0); anT[0] = fmaxf(anT[0], v0); }
            if (ti == tj1) { vap = fminf(vap, v1); apT[1] = fminf(apT[1], v1); }
            else           { van = fmaxf(van, v1); anT[1] = fmaxf(anT[1], v1); }
#pragma unroll
            for (int m = 1; m < 32; m <<= 1) {
                vap = fminf(vap, __shfl_xor(vap, m));
                van = fmaxf(van, __shfl_xor(van, m));
            }
            if (cl == 0) {
                apRed[wc * BT + row] = vap;
                anRed[wc * BT + row] = van;
            }
        }
    }
#pragma unroll
    for (int cg = 0; cg < 2; ++cg) {
        float vap = apT[cg], van = anT[cg];
        vap = fminf(vap, __shfl_xor(vap, 32));
        van = fmaxf(van, __shfl_xor(van, 32));
        if (lane < 32) {
            apRedT[wr * BT + wc * 64 + cg * 32 + cl] = vap;
            anRedT[wr * BT + wc * 64 + cg * 32 + cl] = van;
        }
    }
    __syncthreads();

    if (tid < BT) {
        ap_part[(size_t)bj * N_ROWS + i0 + tid] =
            fminf(apRed[tid], apRed[BT + tid]);
        an_part[(size_t)bj * N_ROWS + i0 + tid] =
            fmaxf(anRed[tid], anRed[BT + tid]);
        if (bi != bj) {
            ap_part[(size_t)bi * N_ROWS + j0 + tid] =
                fminf(apRedT[tid], apRedT[BT + tid]);
            an_part[(size_t)bi * N_ROWS + j0 + tid] =
                fmaxf(anRedT[tid], anRedT[BT + tid]);
        }
    }
}

__global__ __launch_bounds__(256) void fold_kernel(
    const float* __restrict__ ap_part, const float* __restrict__ an_part,
    float* __restrict__ blk_sum, int* __restrict__ counter,
    float* __restrict__ out)
{
    __shared__ float sred[4];
    const int tid = threadIdx.x;
    const int row = blockIdx.x * 256 + tid;
    const int lane = tid & 63;
    const int wave = tid >> 6;

    float ap = FLT_MAX, an = -FLT_MAX;
#pragma unroll 8
    for (int s = 0; s < NTB; ++s) {
        ap = fminf(ap, ap_part[(size_t)s * N_ROWS + row]);
        an = fmaxf(an, an_part[(size_t)s * N_ROWS + row]);
    }
    const float v = an - ap + MARGIN;
    float local = (v > 0.0f) ? v : 0.0f;
#pragma unroll
    for (int m = 32; m >= 1; m >>= 1) local += __shfl_down(local, m);
    if (lane == 0) sred[wave] = local;
    __syncthreads();

    if (tid == 0) {
        blk_sum[blockIdx.x] = sred[0] + sred[1] + sred[2] + sred[3];
        __threadfence();
        if (atomicAdd(counter, 1) == FOLD_BLOCKS - 1) {
            __threadfence();
            float s = 0.0f;
#pragma unroll
            for (int b = 0; b < FOLD_BLOCKS; ++b) s += blk_sum[b];
            out[0] = s * (1.0f / N_ROWS);
        }
    }
}

extern "C" void kernel_launch(void* const* d_in, const int* in_sizes, int n_in,
                              void* d_out, int out_size, void* d_ws, size_t ws_size,
                              hipStream_t stream)
{
    const float* feat = (const float*)d_in[0];
    const int*   tgt  = (const int*)d_in[1];

    ushort_t* fbp     = (ushort_t*)d_ws;                        // 4 MB packed
    float*    ap_part = (float*)(fbp + (size_t)N_ROWS * D_K);   // 512 KB
    float*    an_part = ap_part + (size_t)NTB * N_ROWS;         // 512 KB
    float*    blk_sum = an_part + (size_t)NTB * N_ROWS;         // 64 B
    int*      counter = (int*)(blk_sum + FOLD_BLOCKS);

    cast_kernel<<<N_ROWS / 32, 256, 0, stream>>>(feat, fbp, counter);
    gram_mfma_kernel<<<NTILES, 256, 0, stream>>>(fbp, tgt, ap_part, an_part);
    fold_kernel<<<FOLD_BLOCKS, 256, 0, stream>>>(ap_part, an_part, blk_sum,
                                                 counter, (float*)d_out);
}